// Round 1
// baseline (140.776 us; speedup 1.0000x reference)
//
#include <hip/hip_runtime.h>
#include <math.h>

// Problem constants (fixed by setup_inputs)
#define BB    8
#define DD    64
#define NPIX  32768
#define KK    19
#define PP    5
#define NROW  112   // 7 MFMA tiles x 16 rows (group-aligned 4+1 component split)

typedef _Float16 half8  __attribute__((ext_vector_type(8)));
typedef __fp16   half2t __attribute__((ext_vector_type(2)));   // cvt_pkrtz return type
typedef float    f32x4  __attribute__((ext_vector_type(4)));

union H8 { half8 v; half2t p[4]; };

// ---------------------------------------------------------------------------
// Prep: C table re-laid out so per-group max needs NO transpose.
//  Row R -> (group g, comp p):
//   R <  80 : t=R/16, g = 4t + (R>>2)&3, p = R&3          (comps 0-3; g=19 dummy)
//   R <  96 : g = 4*((R-80)&3) + (R-80)>>2, p = 4          (comp 4, groups 0-15,
//                                                           (q,r)-transpose baked in)
//   R < 112 : g = 16 + (R-96)>>2, p = 4, valid iff (R&3)==0 && g<19
//  C[R][2d] = mn*i2, C[R][2d+1] = -0.5*i2 ; cst[R] = -0.5*c1 - c2
//  (0.5*D*log(2pi) dropped: LN over k is shift-invariant — exact.)
//  scal = {sum(w^2), sum(w*b), sum(b^2)}.
// ---------------------------------------------------------------------------
__global__ __launch_bounds__(64) void gmm_prep(
        const float* __restrict__ means, const float* __restrict__ diag,
        const float* __restrict__ feat_w, const float* __restrict__ feat_b,
        _Float16* __restrict__ Ch, float* __restrict__ cst,
        float* __restrict__ scal) {
    const int R = blockIdx.x;
    const int d = threadIdx.x;
    if (R == NROW) {
        float w = feat_w[d], b = feat_b[d];
        float s0 = w * w, s1 = w * b, s2 = b * b;
        #pragma unroll
        for (int off = 32; off; off >>= 1) {
            s0 += __shfl_xor(s0, off);
            s1 += __shfl_xor(s1, off);
            s2 += __shfl_xor(s2, off);
        }
        if (d == 0) { scal[0] = s0; scal[1] = s1; scal[2] = s2; }
        return;
    }
    int g, p; bool valid;
    if (R < 80)      { g = 4 * (R >> 4) + ((R >> 2) & 3); p = R & 3; valid = (g < KK); }
    else if (R < 96) { g = 4 * ((R - 80) & 3) + ((R - 80) >> 2); p = 4; valid = true; }
    else             { g = 16 + ((R - 96) >> 2); p = 4; valid = ((R & 3) == 0) && (g < KK); }
    if (valid) {
        const int j = 5 * g + p;
        float mu = means[j * DD + d];
        float sc = diag[j * DD + d];
        float ss = mu * mu;
        #pragma unroll
        for (int off = 32; off; off >>= 1) ss += __shfl_xor(ss, off);
        float inv = 1.f / fmaxf(sqrtf(ss), 1e-12f);
        float mn = mu * inv;
        float i2 = 1.f / (sc * sc);
        Ch[R * 128 + 2 * d]     = (_Float16)(mn * i2);
        Ch[R * 128 + 2 * d + 1] = (_Float16)(-0.5f * i2);
        float c1 = mn * mn * i2;
        float c2 = logf(sc);
        #pragma unroll
        for (int off = 32; off; off >>= 1) {
            c1 += __shfl_xor(c1, off);
            c2 += __shfl_xor(c2, off);
        }
        if (d == 0) cst[R] = -0.5f * c1 - c2;   // constant 0.5*D*log(2pi) dropped
    } else {
        Ch[R * 128 + 2 * d]     = (_Float16)0.f;
        Ch[R * 128 + 2 * d + 1] = (_Float16)0.f;
        if (d == 0) cst[R] = 0.f;
    }
}

// ---------------------------------------------------------------------------
// Main: 256 thr = 4 independent waves, 32 px each. ZERO LDS, ZERO barriers.
// Lane (m15 = px-in-tile, q = k-quad) owns groups k = 4t+q (slots t=0..4) for
// its 2 pixels; group max is in-register (tiles 0-4: comps 0-3 per lane-reg,
// tiles 5-6: comp 4 pre-transposed in the table). Mask-LN via 8 shfl_xor.
// launch_bounds(256,4): <=128 VGPR -> 4 waves/SIMD (2x current residency).
// ---------------------------------------------------------------------------
#define DO_TILE(T, MERGE) {                                                   \
    const _Float16* ab = cb + (size_t)((T) * 16 * 128);                       \
    const half8 A0 = *(const half8*)(ab);                                     \
    const half8 A1 = *(const half8*)(ab + 32);                                \
    const half8 A2 = *(const half8*)(ab + 64);                                \
    const half8 A3 = *(const half8*)(ab + 96);                                \
    const float4 cc = *(const float4*)(cst + 16 * (T) + 4 * q);               \
    f32x4 a0 = {0.f, 0.f, 0.f, 0.f}, a1 = {0.f, 0.f, 0.f, 0.f};               \
    a0 = __builtin_amdgcn_mfma_f32_16x16x32_f16(A0, Uh[0][0].v, a0, 0, 0, 0); \
    a1 = __builtin_amdgcn_mfma_f32_16x16x32_f16(A0, Uh[1][0].v, a1, 0, 0, 0); \
    a0 = __builtin_amdgcn_mfma_f32_16x16x32_f16(A1, Uh[0][1].v, a0, 0, 0, 0); \
    a1 = __builtin_amdgcn_mfma_f32_16x16x32_f16(A1, Uh[1][1].v, a1, 0, 0, 0); \
    a0 = __builtin_amdgcn_mfma_f32_16x16x32_f16(A2, Uh[0][2].v, a0, 0, 0, 0); \
    a1 = __builtin_amdgcn_mfma_f32_16x16x32_f16(A2, Uh[1][2].v, a1, 0, 0, 0); \
    a0 = __builtin_amdgcn_mfma_f32_16x16x32_f16(A3, Uh[0][3].v, a0, 0, 0, 0); \
    a1 = __builtin_amdgcn_mfma_f32_16x16x32_f16(A3, Uh[1][3].v, a1, 0, 0, 0); \
    a0 = __builtin_amdgcn_mfma_f32_16x16x32_f16(A0, Ul[0][0].v, a0, 0, 0, 0); \
    a1 = __builtin_amdgcn_mfma_f32_16x16x32_f16(A0, Ul[1][0].v, a1, 0, 0, 0); \
    a0 = __builtin_amdgcn_mfma_f32_16x16x32_f16(A1, Ul[0][1].v, a0, 0, 0, 0); \
    a1 = __builtin_amdgcn_mfma_f32_16x16x32_f16(A1, Ul[1][1].v, a1, 0, 0, 0); \
    a0 = __builtin_amdgcn_mfma_f32_16x16x32_f16(A2, Ul[0][2].v, a0, 0, 0, 0); \
    a1 = __builtin_amdgcn_mfma_f32_16x16x32_f16(A2, Ul[1][2].v, a1, 0, 0, 0); \
    a0 = __builtin_amdgcn_mfma_f32_16x16x32_f16(A3, Ul[0][3].v, a0, 0, 0, 0); \
    a1 = __builtin_amdgcn_mfma_f32_16x16x32_f16(A3, Ul[1][3].v, a1, 0, 0, 0); \
    MERGE                                                                     \
}

#define MERGE_SLOT(T)                                                              \
    m0[T] = fmaxf(fmaxf(a0[0] + cc.x, a0[1] + cc.y), fmaxf(a0[2] + cc.z, a0[3] + cc.w)); \
    m1[T] = fmaxf(fmaxf(a1[0] + cc.x, a1[1] + cc.y), fmaxf(a1[2] + cc.z, a1[3] + cc.w));

#define MERGE_C4A                                                \
    m0[0] = fmaxf(m0[0], a0[0] + cc.x);                          \
    m0[1] = fmaxf(m0[1], a0[1] + cc.y);                          \
    m0[2] = fmaxf(m0[2], a0[2] + cc.z);                          \
    m0[3] = fmaxf(m0[3], a0[3] + cc.w);                          \
    m1[0] = fmaxf(m1[0], a1[0] + cc.x);                          \
    m1[1] = fmaxf(m1[1], a1[1] + cc.y);                          \
    m1[2] = fmaxf(m1[2], a1[2] + cc.z);                          \
    m1[3] = fmaxf(m1[3], a1[3] + cc.w);

#define MERGE_C4B                                                \
    m0[4] = fmaxf(m0[4], a0[0] + cc.x);                          \
    m1[4] = fmaxf(m1[4], a1[0] + cc.x);

__global__ __launch_bounds__(256, 4) void gmm_main(
        const float* __restrict__ bf,
        const float* __restrict__ feat_w, const float* __restrict__ feat_b,
        const float* __restrict__ mask_w, const float* __restrict__ mask_b,
        const _Float16* __restrict__ Ch, const float* __restrict__ cst,
        const float* __restrict__ scal, float* __restrict__ out) {
    const int tid  = threadIdx.x;
    const int w    = tid >> 6;
    const int lane = tid & 63;
    const int m15  = lane & 15;
    const int q    = lane >> 4;
    const int bidx = blockIdx.x;
    const int b    = bidx >> 8;                        // 256 blocks per image
    const int n0   = ((bidx & 255) << 7) + (w << 5);   // wave's 32 pixels

    // ---- global x loads: 2 pixels (tiles) x lane's 16 d's ----
    const float* xp = bf + (size_t)b * (DD * NPIX) + n0 + m15;
    float xs0[16], xs1[16];
    #pragma unroll
    for (int ks = 0; ks < 4; ++ks)
        #pragma unroll
        for (int i = 0; i < 4; ++i) {
            const size_t off = (size_t)(ks * 16 + q * 4 + i) * NPIX;
            xs0[ks * 4 + i] = xp[off];
            xs1[ks * 4 + i] = xp[off + 16];
        }

    float4 wv[4], bv[4];
    #pragma unroll
    for (int ks = 0; ks < 4; ++ks) {
        wv[ks] = *(const float4*)(feat_w + ks * 16 + q * 4);
        bv[ks] = *(const float4*)(feat_b + ks * 16 + q * 4);
    }

    // ---- moments for both pixels; combine the 4 q-lanes per px ----
    float S1a = 0.f, S2a = 0.f, S3a = 0.f, S4a = 0.f, S5a = 0.f;
    float S1b = 0.f, S2b = 0.f, S3b = 0.f, S4b = 0.f, S5b = 0.f;
    #pragma unroll
    for (int ks = 0; ks < 4; ++ks)
        #pragma unroll
        for (int i = 0; i < 4; ++i) {
            float wd = ((const float*)&wv[ks])[i];
            float bd = ((const float*)&bv[ks])[i];
            float xa = xs0[ks * 4 + i], xb = xs1[ks * 4 + i];
            float ta = wd * xa, tb = wd * xb;
            S1a += xa; S2a = fmaf(xa, xa, S2a); S3a = fmaf(ta, ta, S3a);
            S4a = fmaf(ta, wd, S4a); S5a = fmaf(ta, bd, S5a);
            S1b += xb; S2b = fmaf(xb, xb, S2b); S3b = fmaf(tb, tb, S3b);
            S4b = fmaf(tb, wd, S4b); S5b = fmaf(tb, bd, S5b);
        }
    S1a += __shfl_xor(S1a, 16); S1a += __shfl_xor(S1a, 32);
    S2a += __shfl_xor(S2a, 16); S2a += __shfl_xor(S2a, 32);
    S3a += __shfl_xor(S3a, 16); S3a += __shfl_xor(S3a, 32);
    S4a += __shfl_xor(S4a, 16); S4a += __shfl_xor(S4a, 32);
    S5a += __shfl_xor(S5a, 16); S5a += __shfl_xor(S5a, 32);
    S1b += __shfl_xor(S1b, 16); S1b += __shfl_xor(S1b, 32);
    S2b += __shfl_xor(S2b, 16); S2b += __shfl_xor(S2b, 32);
    S3b += __shfl_xor(S3b, 16); S3b += __shfl_xor(S3b, 32);
    S4b += __shfl_xor(S4b, 16); S4b += __shfl_xor(S4b, 32);
    S5b += __shfl_xor(S5b, 16); S5b += __shfl_xor(S5b, 32);

    const float W2 = scal[0], WB = scal[1], B2 = scal[2];
    float al0, e0, f0, al1, e1, f1;
    {
        float mu  = S1a * (1.f / 64.f);
        float var = fmaxf(S2a * (1.f / 64.f) - mu * mu, 0.f);
        float r   = rsqrtf(var + 1e-5f);
        float Sy2 = r * r * (S3a - 2.f * mu * S4a + mu * mu * W2)
                  + 2.f * r * (S5a - mu * WB) + B2;
        float invn = 1.f / fmaxf(sqrtf(fmaxf(Sy2, 0.f)), 1e-12f);
        al0 = invn * r; e0 = invn; f0 = -al0 * mu;
    }
    {
        float mu  = S1b * (1.f / 64.f);
        float var = fmaxf(S2b * (1.f / 64.f) - mu * mu, 0.f);
        float r   = rsqrtf(var + 1e-5f);
        float Sy2 = r * r * (S3b - 2.f * mu * S4b + mu * mu * W2)
                  + 2.f * r * (S5b - mu * WB) + B2;
        float invn = 1.f / fmaxf(sqrtf(fmaxf(Sy2, 0.f)), 1e-12f);
        al1 = invn * r; e1 = invn; f1 = -al1 * mu;
    }

    // ---- build split-fp16 u B-fragments in registers (packed cvt) ----
    H8 Uh[2][4], Ul[2][4];
    #pragma unroll
    for (int ks = 0; ks < 4; ++ks) {
        #pragma unroll
        for (int i = 0; i < 4; ++i) {
            float wd = ((const float*)&wv[ks])[i];
            float bd = ((const float*)&bv[ks])[i];
            float c0 = fmaf(f0, wd, e0 * bd);
            float c1 = fmaf(f1, wd, e1 * bd);
            float u0 = fmaf(al0, wd * xs0[ks * 4 + i], c0);
            float u1 = fmaf(al1, wd * xs1[ks * 4 + i], c1);
            float q0 = u0 * u0, q1 = u1 * u1;
            half2t h0 = __builtin_amdgcn_cvt_pkrtz(u0, q0);   // [u, usq] hi
            half2t h1 = __builtin_amdgcn_cvt_pkrtz(u1, q1);
            half2t l0 = __builtin_amdgcn_cvt_pkrtz(u0 - (float)h0[0], q0 - (float)h0[1]);
            half2t l1 = __builtin_amdgcn_cvt_pkrtz(u1 - (float)h1[0], q1 - (float)h1[1]);
            Uh[0][ks].p[i] = h0; Ul[0][ks].p[i] = l0;
            Uh[1][ks].p[i] = h1; Ul[1][ks].p[i] = l1;
        }
    }

    // ---- 7 tiles x 16 MFMAs; per-group max entirely in registers ----
    const _Float16* cb = Ch + (size_t)m15 * 128 + q * 8;   // A row = m15 of tile
    float m0[5], m1[5];                                    // slots: k = 4t + q
    DO_TILE(0, MERGE_SLOT(0))
    DO_TILE(1, MERGE_SLOT(1))
    DO_TILE(2, MERGE_SLOT(2))
    DO_TILE(3, MERGE_SLOT(3))
    DO_TILE(4, MERGE_SLOT(4))
    DO_TILE(5, MERGE_C4A)
    DO_TILE(6, MERGE_C4B)

    // ---- mask LayerNorm over 19 k's: 8 shfl_xor, no LDS ----
    const bool v4 = (q < 3);                               // slot 4 = k 16+q (<19)
    float S0 = m0[0] + m0[1] + m0[2] + m0[3] + (v4 ? m0[4] : 0.f);
    float S1 = m1[0] + m1[1] + m1[2] + m1[3] + (v4 ? m1[4] : 0.f);
    S0 += __shfl_xor(S0, 16); S0 += __shfl_xor(S0, 32);
    S1 += __shfl_xor(S1, 16); S1 += __shfl_xor(S1, 32);
    const float mu0 = S0 * (1.f / 19.f), mu1 = S1 * (1.f / 19.f);
    float V0, V1;
    {
        float d0 = m0[0] - mu0, d1 = m0[1] - mu0, d2 = m0[2] - mu0;
        float d3 = m0[3] - mu0, d4 = m0[4] - mu0;
        V0 = d0 * d0 + d1 * d1 + d2 * d2 + d3 * d3 + (v4 ? d4 * d4 : 0.f);
    }
    {
        float d0 = m1[0] - mu1, d1 = m1[1] - mu1, d2 = m1[2] - mu1;
        float d3 = m1[3] - mu1, d4 = m1[4] - mu1;
        V1 = d0 * d0 + d1 * d1 + d2 * d2 + d3 * d3 + (v4 ? d4 * d4 : 0.f);
    }
    V0 += __shfl_xor(V0, 16); V0 += __shfl_xor(V0, 32);
    V1 += __shfl_xor(V1, 16); V1 += __shfl_xor(V1, 32);
    const float r0 = rsqrtf(V0 * (1.f / 19.f) + 1e-5f);
    const float r1 = rsqrtf(V1 * (1.f / 19.f) + 1e-5f);

    // ---- stores: lane writes k = 4t+q for its 2 pixels (64B/quad coalesced) ----
    float* op = out + (size_t)b * (KK * NPIX) + n0 + m15;
    #pragma unroll
    for (int t = 0; t < 5; ++t) {
        const int k = 4 * t + q;
        if (t < 4 || v4) {
            const float mw = mask_w[k], mb = mask_b[k];
            op[(size_t)k * NPIX]      = (m0[t] - mu0) * r0 * mw + mb;
            op[(size_t)k * NPIX + 16] = (m1[t] - mu1) * r1 * mw + mb;
        }
    }
}

extern "C" void kernel_launch(void* const* d_in, const int* in_sizes, int n_in,
                              void* d_out, int out_size, void* d_ws, size_t ws_size,
                              hipStream_t stream) {
    const float* base_feature = (const float*)d_in[0]; // [8, 64, 32768]
    const float* means        = (const float*)d_in[1]; // [19, 5, 64]
    const float* diagonal     = (const float*)d_in[2]; // [19, 5, 64]
    const float* feat_w       = (const float*)d_in[3]; // [64]
    const float* feat_b       = (const float*)d_in[4]; // [64]
    const float* mask_w       = (const float*)d_in[5]; // [19]
    const float* mask_b       = (const float*)d_in[6]; // [19]
    float* out = (float*)d_out;                        // [8, 19, 32768] fp32

    // ws layout: Ch[112*128] f16 | cst[112] f32 | scal[3] f32
    _Float16* Ch = (_Float16*)d_ws;
    float* cst   = (float*)(Ch + NROW * 128);
    float* scal  = cst + NROW;

    gmm_prep<<<NROW + 1, 64, 0, stream>>>(means, diagonal, feat_w, feat_b, Ch, cst, scal);

    gmm_main<<<(BB * NPIX) / 128, 256, 0, stream>>>(
        base_feature, feat_w, feat_b, mask_w, mask_b, Ch, cst, scal, out);
}